// Round 1
// baseline (650.623 us; speedup 1.0000x reference)
//
#include <hip/hip_runtime.h>
#include <cstdint>

typedef __attribute__((ext_vector_type(8))) short bf16x8;
typedef __attribute__((ext_vector_type(4))) float f32x4;

__device__ __forceinline__ unsigned short f2bf(float v) {
  unsigned u = __builtin_bit_cast(unsigned, v);
  u += 0x7FFFu + ((u >> 16) & 1u);   // RNE
  return (unsigned short)(u >> 16);
}
__device__ __forceinline__ float bf2f(unsigned short s) {
  unsigned u = ((unsigned)s) << 16;
  return __builtin_bit_cast(float, u);
}

// async global->LDS, 16B per lane; LDS dest = wave-uniform base + lane*16
__device__ __forceinline__ void gload16(const unsigned short* g, unsigned short* l) {
  __builtin_amdgcn_global_load_lds(
      (const __attribute__((address_space(1))) void*)(uintptr_t)g,
      (__attribute__((address_space(3))) void*)(uint32_t)(uintptr_t)l,
      16, 0, 0);
}

// NT GEMM core: C[128x128] += A[128xK] * B[128xK]^T over 3 hi/lo passes.
// A,B already offset to the block's first row. lda/ldb in elements.
__device__ __forceinline__ void gemm_core(
    const unsigned short* __restrict__ Ah, const unsigned short* __restrict__ Al,
    const unsigned short* __restrict__ Bh, const unsigned short* __restrict__ Bl,
    int lda, int ldb, int K,
    unsigned short* ldsA, unsigned short* ldsB, f32x4 acc[4][4])
{
  const int tid  = threadIdx.x;
  const int wave = tid >> 6;
  const int lane = tid & 63;
  const int wm = (wave >> 1) * 64;
  const int wn = (wave & 1) * 64;
  const int lrow = lane & 15;
  const int kq = lane >> 4;
  const int srow = tid >> 2;     // staging row 0..63
  const int schunk = tid & 3;    // 8-elem chunk within 32-elem row

  unsigned short* lA = ldsA + wave * 512;   // bytes: wave*1024
  unsigned short* lB = ldsB + wave * 512;

#pragma unroll 1
  for (int p = 0; p < 3; ++p) {
    const unsigned short* A = (p == 1) ? Al : Ah;
    const unsigned short* B = (p == 2) ? Bl : Bh;
    const unsigned short* ga = A + srow * lda + schunk * 8;
    const unsigned short* gb = B + srow * ldb + schunk * 8;
#pragma unroll 1
    for (int kb = 0; kb < K; kb += 32) {
      __syncthreads();  // previous tile fully consumed
      gload16(ga + kb, lA);
      gload16(ga + kb + 64 * lda, lA + 2048);
      gload16(gb + kb, lB);
      gload16(gb + kb + 64 * ldb, lB + 2048);
      __syncthreads();  // drains vmcnt -> LDS valid
      bf16x8 af[4], bfr[4];
#pragma unroll
      for (int i = 0; i < 4; ++i)
        af[i] = *(const bf16x8*)(ldsA + (wm + i * 16 + lrow) * 32 + kq * 8);
#pragma unroll
      for (int j = 0; j < 4; ++j)
        bfr[j] = *(const bf16x8*)(ldsB + (wn + j * 16 + lrow) * 32 + kq * 8);
#pragma unroll
      for (int i = 0; i < 4; ++i)
#pragma unroll
        for (int j = 0; j < 4; ++j)
          acc[i][j] = __builtin_amdgcn_mfma_f32_16x16x32_bf16(af[i], bfr[j], acc[i][j], 0, 0, 0);
    }
  }
}

// QKV projection: x[8192,1024] * W[1024,1024]^T + b, fused over Q/K/V via blockIdx.y.
// Q,K stored row-major hi/lo; V stored transposed per batch: Vt[b][d][m].
__global__ __launch_bounds__(256, 2) void gemm_qkv(
    const unsigned short* __restrict__ xh, const unsigned short* __restrict__ xl,
    const unsigned short* __restrict__ wh, const unsigned short* __restrict__ wl,
    const float* __restrict__ bq, const float* __restrict__ bk, const float* __restrict__ bv,
    unsigned short* __restrict__ Qh, unsigned short* __restrict__ Ql,
    unsigned short* __restrict__ Kh, unsigned short* __restrict__ Kl,
    unsigned short* __restrict__ Vth, unsigned short* __restrict__ Vtl)
{
  __shared__ __align__(16) unsigned short ldsA[4096];
  __shared__ __align__(16) unsigned short ldsB[4096];
  const int Mblk = blockIdx.x * 128;
  const int sel  = blockIdx.y >> 3;   // 0=Q 1=K 2=V
  const int nb   = blockIdx.y & 7;    // 128-wide col block within 1024

  const unsigned short* Ah = xh + (long)Mblk * 1024;
  const unsigned short* Al = xl + (long)Mblk * 1024;
  const unsigned short* Bh = wh + sel * 1048576 + (long)(nb * 128) * 1024;
  const unsigned short* Bl = wl + sel * 1048576 + (long)(nb * 128) * 1024;
  const float* bias = (sel == 0) ? bq : (sel == 1) ? bk : bv;

  f32x4 acc[4][4] = {};
  gemm_core(Ah, Al, Bh, Bl, 1024, 1024, 1024, ldsA, ldsB, acc);

  const int lane = threadIdx.x & 63, wave = threadIdx.x >> 6;
  const int wm = (wave >> 1) * 64, wn = (wave & 1) * 64;
  const int lrow = lane & 15, kq = lane >> 4;

#pragma unroll
  for (int i = 0; i < 4; ++i) {
#pragma unroll
    for (int j = 0; j < 4; ++j) {
      const int col = nb * 128 + wn + j * 16 + lrow;   // output feature d
      const float bsv = bias[col];
#pragma unroll
      for (int r = 0; r < 4; ++r) {
        const int tok = Mblk + wm + i * 16 + kq * 4 + r;  // token index
        float v = acc[i][j][r] + bsv;
        unsigned short h = f2bf(v);
        unsigned short lo = f2bf(v - bf2f(h));
        if (sel == 2) {
          const long dst = (long)(tok >> 11) * 2097152 + (long)col * 2048 + (tok & 2047);
          Vth[dst] = h; Vtl[dst] = lo;
        } else {
          const long dst = (long)tok * 1024 + col;
          if (sel == 0) { Qh[dst] = h; Ql[dst] = lo; }
          else          { Kh[dst] = h; Kl[dst] = lo; }
        }
      }
    }
  }
}

// Batched NT GEMM with fp32 output: C[z] = alpha * A[z] * B[z]^T
__global__ __launch_bounds__(256, 2) void gemm_f32out(
    const unsigned short* __restrict__ Ah, const unsigned short* __restrict__ Al,
    const unsigned short* __restrict__ Bh, const unsigned short* __restrict__ Bl,
    int lda, int ldb, int K,
    long sA, long sB, float* __restrict__ C, int ldc, long sC, float alpha)
{
  __shared__ __align__(16) unsigned short ldsA[4096];
  __shared__ __align__(16) unsigned short ldsB[4096];
  const int Mblk = blockIdx.x * 128;
  const int Nblk = blockIdx.y * 128;
  const long z = blockIdx.z;
  const unsigned short* Ab  = Ah + z * sA + (long)Mblk * lda;
  const unsigned short* Alb = Al + z * sA + (long)Mblk * lda;
  const unsigned short* Bb  = Bh + z * sB + (long)Nblk * ldb;
  const unsigned short* Blb = Bl + z * sB + (long)Nblk * ldb;
  float* Cb = C + z * sC;

  f32x4 acc[4][4] = {};
  gemm_core(Ab, Alb, Bb, Blb, lda, ldb, K, ldsA, ldsB, acc);

  const int lane = threadIdx.x & 63, wave = threadIdx.x >> 6;
  const int wm = (wave >> 1) * 64, wn = (wave & 1) * 64;
  const int lrow = lane & 15, kq = lane >> 4;
#pragma unroll
  for (int i = 0; i < 4; ++i)
#pragma unroll
    for (int j = 0; j < 4; ++j)
#pragma unroll
      for (int r = 0; r < 4; ++r) {
        const int row = Mblk + wm + i * 16 + kq * 4 + r;
        const int col = Nblk + wn + j * 16 + lrow;
        Cb[(long)row * ldc + col] = alpha * acc[i][j][r];
      }
}

// Row softmax over 2048 entries, in place (fp32) + hi/lo bf16 copy for the PV GEMM.
__global__ __launch_bounds__(256) void softmax_rows(
    float* __restrict__ S, unsigned short* __restrict__ Ph, unsigned short* __restrict__ Pl)
{
  __shared__ float red[4];
  const long row = blockIdx.x;
  float* rp = S + row * 2048;
  const int t = threadIdx.x;

  float x[8];
  *(float4*)&x[0] = reinterpret_cast<const float4*>(rp)[t];
  *(float4*)&x[4] = reinterpret_cast<const float4*>(rp)[t + 256];

  float m = x[0];
#pragma unroll
  for (int i = 1; i < 8; ++i) m = fmaxf(m, x[i]);
  for (int o = 32; o; o >>= 1) m = fmaxf(m, __shfl_xor(m, o, 64));
  if ((t & 63) == 0) red[t >> 6] = m;
  __syncthreads();
  m = fmaxf(fmaxf(red[0], red[1]), fmaxf(red[2], red[3]));
  __syncthreads();

  float s = 0.f;
#pragma unroll
  for (int i = 0; i < 8; ++i) { x[i] = expf(x[i] - m); s += x[i]; }
  for (int o = 32; o; o >>= 1) s += __shfl_xor(s, o, 64);
  if ((t & 63) == 0) red[t >> 6] = s;
  __syncthreads();
  s = (red[0] + red[1]) + (red[2] + red[3]);
  const float inv = 1.0f / s;

#pragma unroll
  for (int i = 0; i < 8; ++i) x[i] *= inv;
  reinterpret_cast<float4*>(rp)[t]       = *(float4*)&x[0];
  reinterpret_cast<float4*>(rp)[t + 256] = *(float4*)&x[4];

  const long b0 = row * 2048 + t * 4;
#pragma unroll
  for (int k = 0; k < 4; ++k) {
    unsigned short h = f2bf(x[k]);
    Ph[b0 + k] = h; Pl[b0 + k] = f2bf(x[k] - bf2f(h));
  }
  const long b1 = row * 2048 + 1024 + t * 4;
#pragma unroll
  for (int k = 0; k < 4; ++k) {
    unsigned short h = f2bf(x[4 + k]);
    Ph[b1 + k] = h; Pl[b1 + k] = f2bf(x[4 + k] - bf2f(h));
  }
}

__global__ __launch_bounds__(256) void split_hi_lo(
    const float* __restrict__ x, unsigned short* __restrict__ hi,
    unsigned short* __restrict__ lo, int n)
{
  int i = blockIdx.x * 256 + threadIdx.x;
  const int stride = gridDim.x * 256;
  for (; i < n; i += stride) {
    float v = x[i];
    unsigned short h = f2bf(v);
    hi[i] = h;
    lo[i] = f2bf(v - bf2f(h));
  }
}

extern "C" void kernel_launch(void* const* d_in, const int* in_sizes, int n_in,
                              void* d_out, int out_size, void* d_ws, size_t ws_size,
                              hipStream_t stream)
{
  const float* x  = (const float*)d_in[0];
  const float* Wq = (const float*)d_in[1];
  const float* bq = (const float*)d_in[2];
  const float* Wk = (const float*)d_in[3];
  const float* bk = (const float*)d_in[4];
  const float* Wv = (const float*)d_in[5];
  const float* bv = (const float*)d_in[6];

  float* out  = (float*)d_out;                 // [4,2048,1024]
  float* attn = (float*)d_out + 8388608;       // [4,2048,2048]

  unsigned short* ws  = (unsigned short*)d_ws;
  unsigned short* xh  = ws;                    //  8,388,608
  unsigned short* xl  = xh + 8388608;
  unsigned short* wh  = xl + 8388608;          //  3,145,728 (Wq|Wk|Wv)
  unsigned short* wl  = wh + 3145728;
  unsigned short* Qh  = wl + 3145728;
  unsigned short* Ql  = Qh + 8388608;
  unsigned short* Kh  = Ql + 8388608;
  unsigned short* Kl  = Kh + 8388608;
  unsigned short* Vth = Kl + 8388608;          // Vt[b][d][m]
  unsigned short* Vtl = Vth + 8388608;
  // P (attention) hi/lo reuse the dead Q/K regions (exactly 16,777,216 each)
  unsigned short* Ph  = Qh;
  unsigned short* Pl  = Kh;

  split_hi_lo<<<4096, 256, 0, stream>>>(x, xh, xl, 8388608);
  split_hi_lo<<<512, 256, 0, stream>>>(Wq, wh, wl, 1048576);
  split_hi_lo<<<512, 256, 0, stream>>>(Wk, wh + 1048576, wl + 1048576, 1048576);
  split_hi_lo<<<512, 256, 0, stream>>>(Wv, wh + 2097152, wl + 2097152, 1048576);

  // Q,K,V projections (M=8192, N=3x1024, K=1024)
  gemm_qkv<<<dim3(64, 24), 256, 0, stream>>>(xh, xl, wh, wl, bq, bk, bv,
                                             Qh, Ql, Kh, Kl, Vth, Vtl);

  // scores = Q K^T / 32  -> fp32 straight into d_out's attention slot
  gemm_f32out<<<dim3(16, 16, 4), 256, 0, stream>>>(Qh, Ql, Kh, Kl, 1024, 1024, 1024,
      2097152L, 2097152L, attn, 2048, 4194304L, 0.03125f);

  // softmax rows in place + emit P hi/lo
  softmax_rows<<<8192, 256, 0, stream>>>(attn, Ph, Pl);

  // out = P * Vt^T
  gemm_f32out<<<dim3(16, 8, 4), 256, 0, stream>>>(Ph, Pl, Vth, Vtl, 2048, 2048, 2048,
      4194304L, 2097152L, out, 1024, 2097152L, 1.0f);
}

// Round 2
// 565.783 us; speedup vs baseline: 1.1499x; 1.1499x over previous
//
#include <hip/hip_runtime.h>
#include <cstdint>

typedef __attribute__((ext_vector_type(8))) short bf16x8;
typedef __attribute__((ext_vector_type(4))) float f32x4;

__device__ __forceinline__ unsigned short f2bf(float v) {
  unsigned u = __builtin_bit_cast(unsigned, v);
  u += 0x7FFFu + ((u >> 16) & 1u);   // RNE
  return (unsigned short)(u >> 16);
}
__device__ __forceinline__ float bf2f(unsigned short s) {
  unsigned u = ((unsigned)s) << 16;
  return __builtin_bit_cast(float, u);
}

// async global->LDS, 16B per lane; LDS dest = wave-uniform base + lane*16
__device__ __forceinline__ void gload16(const unsigned short* g, unsigned short* l) {
  __builtin_amdgcn_global_load_lds(
      (const __attribute__((address_space(1))) void*)(uintptr_t)g,
      (__attribute__((address_space(3))) void*)(uint32_t)(uintptr_t)l,
      16, 0, 0);
}

// Fused split-bf16 NT GEMM core: C[128x128] += Ah*Bh^T + Al*Bh^T + Ah*Bl^T
// in ONE K-sweep (48 MFMA per barrier pair). LDS tiles are XOR-swizzled:
// row r's 16B chunk c lives at physical chunk c ^ ((r>>1)&3), which spreads
// the 16-row ds_read_b128 across all 32 banks (2-way only => free).
__device__ __forceinline__ void gemm_core(
    const unsigned short* __restrict__ Ah, const unsigned short* __restrict__ Al,
    const unsigned short* __restrict__ Bh, const unsigned short* __restrict__ Bl,
    int lda, int ldb, int K,
    unsigned short* ldsA, unsigned short* ldsB, f32x4 acc[4][4])
{
  const int tid  = threadIdx.x;
  const int wave = tid >> 6;
  const int lane = tid & 63;
  const int wm = (wave >> 1) * 64;
  const int wn = (wave & 1) * 64;
  const int lrow = lane & 15;
  const int kq = lane >> 4;
  const int srow = wave * 16 + (lane >> 2);             // staging row 0..63
  const int sch  = (lane & 3) ^ ((lane >> 3) & 3);      // swizzled chunk fetch

  unsigned short* lAh = ldsA + wave * 512;              // hi tile, this wave's slice
  unsigned short* lAl = ldsA + 4096 + wave * 512;       // lo tile
  unsigned short* lBh = ldsB + wave * 512;
  unsigned short* lBl = ldsB + 4096 + wave * 512;

  const unsigned short* gah = Ah + (long)srow * lda + sch * 8;
  const unsigned short* gal = Al + (long)srow * lda + sch * 8;
  const unsigned short* gbh = Bh + (long)srow * ldb + sch * 8;
  const unsigned short* gbl = Bl + (long)srow * ldb + sch * 8;
  const long a64 = (long)64 * lda;
  const long b64 = (long)64 * ldb;

  const int pc = (kq ^ ((lrow >> 1) & 3)) * 8;          // swizzled read chunk (shorts)

#pragma unroll 1
  for (int kb = 0; kb < K; kb += 32) {
    __syncthreads();  // previous tile fully consumed
    gload16(gah + kb, lAh);        gload16(gah + kb + a64, lAh + 2048);
    gload16(gal + kb, lAl);        gload16(gal + kb + a64, lAl + 2048);
    gload16(gbh + kb, lBh);        gload16(gbh + kb + b64, lBh + 2048);
    gload16(gbl + kb, lBl);        gload16(gbl + kb + b64, lBl + 2048);
    __syncthreads();  // drains vmcnt -> LDS valid

    bf16x8 ah[4], bh[4], t[4];
#pragma unroll
    for (int i = 0; i < 4; ++i)
      ah[i] = *(const bf16x8*)(ldsA + (wm + i * 16 + lrow) * 32 + pc);
#pragma unroll
    for (int j = 0; j < 4; ++j)
      bh[j] = *(const bf16x8*)(ldsB + (wn + j * 16 + lrow) * 32 + pc);
#pragma unroll
    for (int i = 0; i < 4; ++i)
#pragma unroll
      for (int j = 0; j < 4; ++j)
        acc[i][j] = __builtin_amdgcn_mfma_f32_16x16x32_bf16(ah[i], bh[j], acc[i][j], 0, 0, 0);

#pragma unroll
    for (int i = 0; i < 4; ++i)
      t[i] = *(const bf16x8*)(ldsA + 4096 + (wm + i * 16 + lrow) * 32 + pc);  // Al
#pragma unroll
    for (int i = 0; i < 4; ++i)
#pragma unroll
      for (int j = 0; j < 4; ++j)
        acc[i][j] = __builtin_amdgcn_mfma_f32_16x16x32_bf16(t[i], bh[j], acc[i][j], 0, 0, 0);

#pragma unroll
    for (int j = 0; j < 4; ++j)
      t[j] = *(const bf16x8*)(ldsB + 4096 + (wn + j * 16 + lrow) * 32 + pc);  // Bl
#pragma unroll
    for (int i = 0; i < 4; ++i)
#pragma unroll
      for (int j = 0; j < 4; ++j)
        acc[i][j] = __builtin_amdgcn_mfma_f32_16x16x32_bf16(ah[i], t[j], acc[i][j], 0, 0, 0);
  }
}

// QKV projection: x[8192,1024] * W[1024,1024]^T + b, fused over Q/K/V via blockIdx.y.
// Q,K stored row-major hi/lo; V stored transposed per batch: Vt[b][d][m].
__global__ __launch_bounds__(256, 2) void gemm_qkv(
    const unsigned short* __restrict__ xh, const unsigned short* __restrict__ xl,
    const unsigned short* __restrict__ wh, const unsigned short* __restrict__ wl,
    const float* __restrict__ bq, const float* __restrict__ bk, const float* __restrict__ bv,
    unsigned short* __restrict__ Qh, unsigned short* __restrict__ Ql,
    unsigned short* __restrict__ Kh, unsigned short* __restrict__ Kl,
    unsigned short* __restrict__ Vth, unsigned short* __restrict__ Vtl)
{
  __shared__ __align__(16) unsigned short ldsA[8192];
  __shared__ __align__(16) unsigned short ldsB[8192];
  const int Mblk = blockIdx.x * 128;
  const int sel  = blockIdx.y >> 3;   // 0=Q 1=K 2=V
  const int nb   = blockIdx.y & 7;    // 128-wide col block within 1024

  const unsigned short* Ah = xh + (long)Mblk * 1024;
  const unsigned short* Al = xl + (long)Mblk * 1024;
  const unsigned short* Bh = wh + sel * 1048576 + (long)(nb * 128) * 1024;
  const unsigned short* Bl = wl + sel * 1048576 + (long)(nb * 128) * 1024;
  const float* bias = (sel == 0) ? bq : (sel == 1) ? bk : bv;

  f32x4 acc[4][4] = {};
  gemm_core(Ah, Al, Bh, Bl, 1024, 1024, 1024, ldsA, ldsB, acc);

  const int lane = threadIdx.x & 63, wave = threadIdx.x >> 6;
  const int wm = (wave >> 1) * 64, wn = (wave & 1) * 64;
  const int lrow = lane & 15, kq = lane >> 4;

#pragma unroll
  for (int i = 0; i < 4; ++i) {
#pragma unroll
    for (int j = 0; j < 4; ++j) {
      const int col = nb * 128 + wn + j * 16 + lrow;   // output feature d
      const float bsv = bias[col];
#pragma unroll
      for (int r = 0; r < 4; ++r) {
        const int tok = Mblk + wm + i * 16 + kq * 4 + r;  // token index
        float v = acc[i][j][r] + bsv;
        unsigned short h = f2bf(v);
        unsigned short lo = f2bf(v - bf2f(h));
        if (sel == 2) {
          const long dst = (long)(tok >> 11) * 2097152 + (long)col * 2048 + (tok & 2047);
          Vth[dst] = h; Vtl[dst] = lo;
        } else {
          const long dst = (long)tok * 1024 + col;
          if (sel == 0) { Qh[dst] = h; Ql[dst] = lo; }
          else          { Kh[dst] = h; Kl[dst] = lo; }
        }
      }
    }
  }
}

// Batched NT GEMM with fp32 output: C[z] = alpha * A[z] * B[z]^T
__global__ __launch_bounds__(256, 2) void gemm_f32out(
    const unsigned short* __restrict__ Ah, const unsigned short* __restrict__ Al,
    const unsigned short* __restrict__ Bh, const unsigned short* __restrict__ Bl,
    int lda, int ldb, int K,
    long sA, long sB, float* __restrict__ C, int ldc, long sC, float alpha)
{
  __shared__ __align__(16) unsigned short ldsA[8192];
  __shared__ __align__(16) unsigned short ldsB[8192];
  const int Mblk = blockIdx.x * 128;
  const int Nblk = blockIdx.y * 128;
  const long z = blockIdx.z;
  const unsigned short* Ab  = Ah + z * sA + (long)Mblk * lda;
  const unsigned short* Alb = Al + z * sA + (long)Mblk * lda;
  const unsigned short* Bb  = Bh + z * sB + (long)Nblk * ldb;
  const unsigned short* Blb = Bl + z * sB + (long)Nblk * ldb;
  float* Cb = C + z * sC;

  f32x4 acc[4][4] = {};
  gemm_core(Ab, Alb, Bb, Blb, lda, ldb, K, ldsA, ldsB, acc);

  const int lane = threadIdx.x & 63, wave = threadIdx.x >> 6;
  const int wm = (wave >> 1) * 64, wn = (wave & 1) * 64;
  const int lrow = lane & 15, kq = lane >> 4;
#pragma unroll
  for (int i = 0; i < 4; ++i)
#pragma unroll
    for (int j = 0; j < 4; ++j)
#pragma unroll
      for (int r = 0; r < 4; ++r) {
        const int row = Mblk + wm + i * 16 + kq * 4 + r;
        const int col = Nblk + wn + j * 16 + lrow;
        Cb[(long)row * ldc + col] = alpha * acc[i][j][r];
      }
}

// Row softmax over 2048 entries, in place (fp32) + hi/lo bf16 copy for the PV GEMM.
__global__ __launch_bounds__(256) void softmax_rows(
    float* __restrict__ S, unsigned short* __restrict__ Ph, unsigned short* __restrict__ Pl)
{
  __shared__ float red[4];
  const long row = blockIdx.x;
  float* rp = S + row * 2048;
  const int t = threadIdx.x;

  float x[8];
  *(float4*)&x[0] = reinterpret_cast<const float4*>(rp)[t];
  *(float4*)&x[4] = reinterpret_cast<const float4*>(rp)[t + 256];

  float m = x[0];
#pragma unroll
  for (int i = 1; i < 8; ++i) m = fmaxf(m, x[i]);
  for (int o = 32; o; o >>= 1) m = fmaxf(m, __shfl_xor(m, o, 64));
  if ((t & 63) == 0) red[t >> 6] = m;
  __syncthreads();
  m = fmaxf(fmaxf(red[0], red[1]), fmaxf(red[2], red[3]));
  __syncthreads();

  float s = 0.f;
#pragma unroll
  for (int i = 0; i < 8; ++i) { x[i] = expf(x[i] - m); s += x[i]; }
  for (int o = 32; o; o >>= 1) s += __shfl_xor(s, o, 64);
  if ((t & 63) == 0) red[t >> 6] = s;
  __syncthreads();
  s = (red[0] + red[1]) + (red[2] + red[3]);
  const float inv = 1.0f / s;

#pragma unroll
  for (int i = 0; i < 8; ++i) x[i] *= inv;
  reinterpret_cast<float4*>(rp)[t]       = *(float4*)&x[0];
  reinterpret_cast<float4*>(rp)[t + 256] = *(float4*)&x[4];

  const long b0 = row * 2048 + t * 4;
#pragma unroll
  for (int k = 0; k < 4; ++k) {
    unsigned short h = f2bf(x[k]);
    Ph[b0 + k] = h; Pl[b0 + k] = f2bf(x[k] - bf2f(h));
  }
  const long b1 = row * 2048 + 1024 + t * 4;
#pragma unroll
  for (int k = 0; k < 4; ++k) {
    unsigned short h = f2bf(x[4 + k]);
    Ph[b1 + k] = h; Pl[b1 + k] = f2bf(x[4 + k] - bf2f(h));
  }
}

__global__ __launch_bounds__(256) void split_hi_lo(
    const float* __restrict__ x, unsigned short* __restrict__ hi,
    unsigned short* __restrict__ lo, int n)
{
  int i = blockIdx.x * 256 + threadIdx.x;
  const int stride = gridDim.x * 256;
  for (; i < n; i += stride) {
    float v = x[i];
    unsigned short h = f2bf(v);
    hi[i] = h;
    lo[i] = f2bf(v - bf2f(h));
  }
}

extern "C" void kernel_launch(void* const* d_in, const int* in_sizes, int n_in,
                              void* d_out, int out_size, void* d_ws, size_t ws_size,
                              hipStream_t stream)
{
  const float* x  = (const float*)d_in[0];
  const float* Wq = (const float*)d_in[1];
  const float* bq = (const float*)d_in[2];
  const float* Wk = (const float*)d_in[3];
  const float* bk = (const float*)d_in[4];
  const float* Wv = (const float*)d_in[5];
  const float* bv = (const float*)d_in[6];

  float* out  = (float*)d_out;                 // [4,2048,1024]
  float* attn = (float*)d_out + 8388608;       // [4,2048,2048]

  unsigned short* ws  = (unsigned short*)d_ws;
  unsigned short* xh  = ws;                    //  8,388,608
  unsigned short* xl  = xh + 8388608;
  unsigned short* wh  = xl + 8388608;          //  3,145,728 (Wq|Wk|Wv)
  unsigned short* wl  = wh + 3145728;
  unsigned short* Qh  = wl + 3145728;
  unsigned short* Ql  = Qh + 8388608;
  unsigned short* Kh  = Ql + 8388608;
  unsigned short* Kl  = Kh + 8388608;
  unsigned short* Vth = Kl + 8388608;          // Vt[b][d][m]
  unsigned short* Vtl = Vth + 8388608;
  // P (attention) hi/lo reuse the dead Q/K regions (exactly 16,777,216 each)
  unsigned short* Ph  = Qh;
  unsigned short* Pl  = Kh;

  split_hi_lo<<<4096, 256, 0, stream>>>(x, xh, xl, 8388608);
  split_hi_lo<<<512, 256, 0, stream>>>(Wq, wh, wl, 1048576);
  split_hi_lo<<<512, 256, 0, stream>>>(Wk, wh + 1048576, wl + 1048576, 1048576);
  split_hi_lo<<<512, 256, 0, stream>>>(Wv, wh + 2097152, wl + 2097152, 1048576);

  // Q,K,V projections (M=8192, N=3x1024, K=1024)
  gemm_qkv<<<dim3(64, 24), 256, 0, stream>>>(xh, xl, wh, wl, bq, bk, bv,
                                             Qh, Ql, Kh, Kl, Vth, Vtl);

  // scores = Q K^T / 32  -> fp32 straight into d_out's attention slot
  gemm_f32out<<<dim3(16, 16, 4), 256, 0, stream>>>(Qh, Ql, Kh, Kl, 1024, 1024, 1024,
      2097152L, 2097152L, attn, 2048, 4194304L, 0.03125f);

  // softmax rows in place + emit P hi/lo
  softmax_rows<<<8192, 256, 0, stream>>>(attn, Ph, Pl);

  // out = P * Vt^T
  gemm_f32out<<<dim3(16, 8, 4), 256, 0, stream>>>(Ph, Pl, Vth, Vtl, 2048, 2048, 2048,
      4194304L, 2097152L, out, 1024, 2097152L, 1.0f);
}

// Round 3
// 317.067 us; speedup vs baseline: 2.0520x; 1.7844x over previous
//
#include <hip/hip_runtime.h>
#include <cstdint>

typedef __attribute__((ext_vector_type(8))) short bf16x8;
typedef __attribute__((ext_vector_type(4))) float f32x4;

__device__ __forceinline__ unsigned short f2bf(float v) {
  unsigned u = __builtin_bit_cast(unsigned, v);
  u += 0x7FFFu + ((u >> 16) & 1u);   // RNE
  return (unsigned short)(u >> 16);
}

// async global->LDS, 16B per lane; LDS dest = wave-uniform base + lane*16
__device__ __forceinline__ void gload16(const unsigned short* g, unsigned short* l) {
  __builtin_amdgcn_global_load_lds(
      (const __attribute__((address_space(1))) void*)(uintptr_t)g,
      (__attribute__((address_space(3))) void*)(uint32_t)(uintptr_t)l,
      16, 0, 0);
}

// Single-pass bf16 NT GEMM core: C[128x128] += A[128xK] * B[128xK]^T, BK=64.
// LDS tile 128 rows x 64 shorts (128 B/row, 8 chunks of 16B). XOR swizzle:
// row r's logical 16B chunk c lives at physical chunk c ^ (r&7) -> the
// 16-row ds_read_b128 spreads over 8 chunks (2-way per bank = free), and the
// staging side stays lane-contiguous for global_load_lds.
__device__ __forceinline__ void gemm_core(
    const unsigned short* __restrict__ A, const unsigned short* __restrict__ B,
    int lda, int ldb, int K,
    unsigned short* ldsA, unsigned short* ldsB, f32x4 acc[4][4])
{
  const int tid  = threadIdx.x;
  const int wave = tid >> 6;
  const int lane = tid & 63;
  const int wm = (wave >> 1) * 64;
  const int wn = (wave & 1) * 64;
  const int lrow = lane & 15;
  const int kq = lane >> 4;

  // staging: wave w fills rows [w*32, w*32+32); lane covers row w*32+i*8+(lane>>3),
  // swizzled chunk (lane&7)^((lane>>3)&7); 4 calls per operand per K-chunk.
  const int sr = lane >> 3;                       // 0..7
  const int sc = (lane & 7) ^ (sr & 7);           // swizzled source chunk
  const unsigned short* ga = A + (long)(wave * 32 + sr) * lda + sc * 8;
  const unsigned short* gb = B + (long)(wave * 32 + sr) * ldb + sc * 8;
  unsigned short* lA = ldsA + wave * 2048;        // 4 KB slice per wave
  unsigned short* lB = ldsB + wave * 2048;

  const int pc0 = ((0 * 4 + kq) ^ (lrow & 7)) * 8;   // k-step 0 read chunk
  const int pc1 = ((1 * 4 + kq) ^ (lrow & 7)) * 8;   // k-step 1 read chunk

#pragma unroll 1
  for (int kb = 0; kb < K; kb += 64) {
    __syncthreads();  // previous tile fully consumed
#pragma unroll
    for (int i = 0; i < 4; ++i) {
      gload16(ga + kb + (long)i * 8 * lda, lA + i * 512);
      gload16(gb + kb + (long)i * 8 * ldb, lB + i * 512);
    }
    __syncthreads();  // drains vmcnt -> LDS valid

    bf16x8 af[4], bfr[4];
    // k-step 0 (k = kb .. kb+31)
#pragma unroll
    for (int i = 0; i < 4; ++i)
      af[i] = *(const bf16x8*)(ldsA + (wm + i * 16 + lrow) * 64 + pc0);
#pragma unroll
    for (int j = 0; j < 4; ++j)
      bfr[j] = *(const bf16x8*)(ldsB + (wn + j * 16 + lrow) * 64 + pc0);
#pragma unroll
    for (int i = 0; i < 4; ++i)
#pragma unroll
      for (int j = 0; j < 4; ++j)
        acc[i][j] = __builtin_amdgcn_mfma_f32_16x16x32_bf16(af[i], bfr[j], acc[i][j], 0, 0, 0);

    // k-step 1 (k = kb+32 .. kb+63)
#pragma unroll
    for (int i = 0; i < 4; ++i)
      af[i] = *(const bf16x8*)(ldsA + (wm + i * 16 + lrow) * 64 + pc1);
#pragma unroll
    for (int j = 0; j < 4; ++j)
      bfr[j] = *(const bf16x8*)(ldsB + (wn + j * 16 + lrow) * 64 + pc1);
#pragma unroll
    for (int i = 0; i < 4; ++i)
#pragma unroll
      for (int j = 0; j < 4; ++j)
        acc[i][j] = __builtin_amdgcn_mfma_f32_16x16x32_bf16(af[i], bfr[j], acc[i][j], 0, 0, 0);
  }
}

// QKV projection: x[8192,1024] * W[1024,1024]^T + b, fused over Q/K/V via blockIdx.y.
// Q,K stored row-major bf16; V stored transposed per batch: Vt[b][d][m].
__global__ __launch_bounds__(256, 4) void gemm_qkv(
    const unsigned short* __restrict__ xh,
    const unsigned short* __restrict__ wh,
    const float* __restrict__ bq, const float* __restrict__ bk, const float* __restrict__ bv,
    unsigned short* __restrict__ Qh, unsigned short* __restrict__ Kh,
    unsigned short* __restrict__ Vth)
{
  __shared__ __align__(16) unsigned short ldsA[8192];
  __shared__ __align__(16) unsigned short ldsB[8192];
  const int Mblk = blockIdx.x * 128;
  const int sel  = blockIdx.y >> 3;   // 0=Q 1=K 2=V
  const int nb   = blockIdx.y & 7;    // 128-wide col block within 1024

  const unsigned short* A = xh + (long)Mblk * 1024;
  const unsigned short* B = wh + sel * 1048576 + (long)(nb * 128) * 1024;
  const float* bias = (sel == 0) ? bq : (sel == 1) ? bk : bv;

  f32x4 acc[4][4] = {};
  gemm_core(A, B, 1024, 1024, 1024, ldsA, ldsB, acc);

  const int lane = threadIdx.x & 63, wave = threadIdx.x >> 6;
  const int wm = (wave >> 1) * 64, wn = (wave & 1) * 64;
  const int lrow = lane & 15, kq = lane >> 4;

#pragma unroll
  for (int i = 0; i < 4; ++i) {
#pragma unroll
    for (int j = 0; j < 4; ++j) {
      const int col = nb * 128 + wn + j * 16 + lrow;   // output feature d
      const float bsv = bias[col];
#pragma unroll
      for (int r = 0; r < 4; ++r) {
        const int tok = Mblk + wm + i * 16 + kq * 4 + r;  // token index
        const unsigned short h = f2bf(acc[i][j][r] + bsv);
        if (sel == 2) {
          Vth[(long)(tok >> 11) * 2097152 + (long)col * 2048 + (tok & 2047)] = h;
        } else if (sel == 0) {
          Qh[(long)tok * 1024 + col] = h;
        } else {
          Kh[(long)tok * 1024 + col] = h;
        }
      }
    }
  }
}

// Batched NT GEMM with fp32 output: C[z] = alpha * A[z] * B[z]^T
__global__ __launch_bounds__(256, 4) void gemm_f32out(
    const unsigned short* __restrict__ A, const unsigned short* __restrict__ B,
    int lda, int ldb, int K,
    long sA, long sB, float* __restrict__ C, int ldc, long sC, float alpha)
{
  __shared__ __align__(16) unsigned short ldsA[8192];
  __shared__ __align__(16) unsigned short ldsB[8192];
  const int Mblk = blockIdx.x * 128;
  const int Nblk = blockIdx.y * 128;
  const long z = blockIdx.z;
  const unsigned short* Ab = A + z * sA + (long)Mblk * lda;
  const unsigned short* Bb = B + z * sB + (long)Nblk * ldb;
  float* Cb = C + z * sC;

  f32x4 acc[4][4] = {};
  gemm_core(Ab, Bb, lda, ldb, K, ldsA, ldsB, acc);

  const int lane = threadIdx.x & 63, wave = threadIdx.x >> 6;
  const int wm = (wave >> 1) * 64, wn = (wave & 1) * 64;
  const int lrow = lane & 15, kq = lane >> 4;
#pragma unroll
  for (int i = 0; i < 4; ++i)
#pragma unroll
    for (int j = 0; j < 4; ++j)
#pragma unroll
      for (int r = 0; r < 4; ++r) {
        const int row = Mblk + wm + i * 16 + kq * 4 + r;
        const int col = Nblk + wn + j * 16 + lrow;
        Cb[(long)row * ldc + col] = alpha * acc[i][j][r];
      }
}

// Row softmax over 2048 entries, in place (fp32) + bf16 copy for the PV GEMM.
__global__ __launch_bounds__(256) void softmax_rows(
    float* __restrict__ S, unsigned short* __restrict__ Ph)
{
  __shared__ float red[4];
  const long row = blockIdx.x;
  float* rp = S + row * 2048;
  const int t = threadIdx.x;

  float x[8];
  *(float4*)&x[0] = reinterpret_cast<const float4*>(rp)[t];
  *(float4*)&x[4] = reinterpret_cast<const float4*>(rp)[t + 256];

  float m = x[0];
#pragma unroll
  for (int i = 1; i < 8; ++i) m = fmaxf(m, x[i]);
  for (int o = 32; o; o >>= 1) m = fmaxf(m, __shfl_xor(m, o, 64));
  if ((t & 63) == 0) red[t >> 6] = m;
  __syncthreads();
  m = fmaxf(fmaxf(red[0], red[1]), fmaxf(red[2], red[3]));
  __syncthreads();

  float s = 0.f;
#pragma unroll
  for (int i = 0; i < 8; ++i) { x[i] = expf(x[i] - m); s += x[i]; }
  for (int o = 32; o; o >>= 1) s += __shfl_xor(s, o, 64);
  if ((t & 63) == 0) red[t >> 6] = s;
  __syncthreads();
  s = (red[0] + red[1]) + (red[2] + red[3]);
  const float inv = 1.0f / s;

#pragma unroll
  for (int i = 0; i < 8; ++i) x[i] *= inv;
  reinterpret_cast<float4*>(rp)[t]       = *(float4*)&x[0];
  reinterpret_cast<float4*>(rp)[t + 256] = *(float4*)&x[4];

  const long b0 = row * 2048 + t * 4;
#pragma unroll
  for (int k = 0; k < 4; ++k) Ph[b0 + k] = f2bf(x[k]);
  const long b1 = row * 2048 + 1024 + t * 4;
#pragma unroll
  for (int k = 0; k < 4; ++k) Ph[b1 + k] = f2bf(x[4 + k]);
}

__global__ __launch_bounds__(256) void to_bf16(
    const float* __restrict__ x, unsigned short* __restrict__ hi, int n)
{
  int i = blockIdx.x * 256 + threadIdx.x;
  const int stride = gridDim.x * 256;
  for (; i < n; i += stride) hi[i] = f2bf(x[i]);
}

extern "C" void kernel_launch(void* const* d_in, const int* in_sizes, int n_in,
                              void* d_out, int out_size, void* d_ws, size_t ws_size,
                              hipStream_t stream)
{
  const float* x  = (const float*)d_in[0];
  const float* Wq = (const float*)d_in[1];
  const float* bq = (const float*)d_in[2];
  const float* Wk = (const float*)d_in[3];
  const float* bk = (const float*)d_in[4];
  const float* Wv = (const float*)d_in[5];
  const float* bv = (const float*)d_in[6];

  float* out  = (float*)d_out;                 // [4,2048,1024]
  float* attn = (float*)d_out + 8388608;       // [4,2048,2048]

  unsigned short* ws  = (unsigned short*)d_ws;
  unsigned short* xh  = ws;                    //  8,388,608
  unsigned short* wh  = xh + 8388608;          //  3,145,728 (Wq|Wk|Wv)
  unsigned short* Qh  = wh + 3145728;          //  8,388,608
  unsigned short* Kh  = Qh + 8388608;          //  8,388,608
  unsigned short* Vth = Kh + 8388608;          //  8,388,608  Vt[b][d][m]
  unsigned short* Ph  = Vth + 8388608;         // 16,777,216  P bf16

  to_bf16<<<4096, 256, 0, stream>>>(x, xh, 8388608);
  to_bf16<<<512, 256, 0, stream>>>(Wq, wh, 1048576);
  to_bf16<<<512, 256, 0, stream>>>(Wk, wh + 1048576, 1048576);
  to_bf16<<<512, 256, 0, stream>>>(Wv, wh + 2097152, 1048576);

  // Q,K,V projections (M=8192, N=3x1024, K=1024)
  gemm_qkv<<<dim3(64, 24), 256, 0, stream>>>(xh, wh, bq, bk, bv, Qh, Kh, Vth);

  // scores = Q K^T / 32  -> fp32 straight into d_out's attention slot
  gemm_f32out<<<dim3(16, 16, 4), 256, 0, stream>>>(Qh, Kh, 1024, 1024, 1024,
      2097152L, 2097152L, attn, 2048, 4194304L, 0.03125f);

  // softmax rows in place + emit P bf16
  softmax_rows<<<8192, 256, 0, stream>>>(attn, Ph);

  // out = P * Vt^T
  gemm_f32out<<<dim3(16, 8, 4), 256, 0, stream>>>(Ph, Vth, 2048, 2048, 2048,
      4194304L, 2097152L, out, 1024, 2097152L, 1.0f);
}